// Round 4
// baseline (1521.209 us; speedup 1.0000x reference)
//
#include <hip/hip_runtime.h>

// DRNet scan: 256 workgroups x 512 threads; each wg owns 16 batch rows and
// iterates all 256 timesteps locally. GEMM: mfma_f32_16x16x32_bf16 with
// 3-level bf16 split of latent and W_hh, SIX term products per tile
// (AhWh + AmWh + AhWm + AlWh + AhWl + AmWm; dropped terms are 2^-27) ->
// matmul error at generic-fp32-noise level. RNG: bit-exact JAX threefry2x32
// partitionable semantics + XLA ErfInv f32 with log1p-matching tail
// handling, on the VALU concurrently with the MFMA pipe.
// Error ladder: 2-level/5-term=45.5 -> 3-level/5-term=16.5 (dropped AmWm
// at 2^-18 was dominant) -> this round adds AmWm + tail-exact log.

#define TSTEPS 256
#define HDIM   256
#define ROWS   16
#define LSTR   264   // bf16 LDS row stride (pad 8 -> 2-way bank aliasing only, free)
#define XSTR   260   // f32 x-stage stride

typedef __attribute__((ext_vector_type(8))) short short8;
typedef __attribute__((ext_vector_type(4))) float float4v;
typedef __bf16 bf16x8 __attribute__((ext_vector_type(8)));

struct U2 { unsigned x, y; };

__device__ __forceinline__ void tfround(unsigned &x0, unsigned &x1, const int r) {
  x0 += x1;
  x1 = __builtin_rotateleft32(x1, r);
  x1 ^= x0;
}

// Threefry-2x32, 20 rounds (Random123 / JAX threefry2x32_p)
__device__ __forceinline__ U2 threefry(unsigned k0, unsigned k1, unsigned x0, unsigned x1) {
  unsigned k2 = k0 ^ k1 ^ 0x1BD11BDAu;
  x0 += k0; x1 += k1;
  tfround(x0,x1,13); tfround(x0,x1,15); tfround(x0,x1,26); tfround(x0,x1,6);
  x0 += k1; x1 += k2 + 1u;
  tfround(x0,x1,17); tfround(x0,x1,29); tfround(x0,x1,16); tfround(x0,x1,24);
  x0 += k2; x1 += k0 + 2u;
  tfround(x0,x1,13); tfround(x0,x1,15); tfround(x0,x1,26); tfround(x0,x1,6);
  x0 += k0; x1 += k1 + 3u;
  tfround(x0,x1,17); tfround(x0,x1,29); tfround(x0,x1,16); tfround(x0,x1,24);
  x0 += k1; x1 += k2 + 4u;
  tfround(x0,x1,13); tfround(x0,x1,15); tfround(x0,x1,26); tfround(x0,x1,6);
  x0 += k2; x1 += k0 + 5u;
  return {x0, x1};
}

// JAX uniform(lo=nextafter(-1,0), hi=1) -> sqrt(2)*erf_inv(u), XLA ErfInv32.
// Tail-exact: w = -log1p(-(u*u)) semantics = -log(1 - t1) with t1 = rounded
// u^2 and an UNFUSED subtract (Sterbenz-exact for t1>=0.5 -> matches np/XLA
// in the tail where the result is amplification-sensitive).
__device__ __forceinline__ float jax_normal_from_bits(unsigned bits) {
#pragma clang fp contract(off)
  const float LO = __builtin_bit_cast(float, 0xBF7FFFFFu); // nextafter(-1,0)
  float f = __builtin_bit_cast(float, (bits >> 9) | 0x3f800000u) - 1.0f;
  float u = fmaf(f, 2.0f, LO);  // f*2 exact; (1-lo) rounds to 2.0f RNE
  u = fmaxf(u, LO);
  float t1 = u * u;             // rounded u^2 (as XLA's x*x)
  float s  = 1.0f - t1;         // exact for t1>=0.5 (Sterbenz); no fma contract
  float w  = -0.6931471805599453f * __builtin_amdgcn_logf(s);
  float p;
  if (w < 5.0f) {
    float z = w - 2.5f;
    p = 2.81022636e-08f;
    p = fmaf(p, z, 3.43273939e-07f);
    p = fmaf(p, z, -3.5233877e-06f);
    p = fmaf(p, z, -4.39150654e-06f);
    p = fmaf(p, z, 0.00021858087f);
    p = fmaf(p, z, -0.00125372503f);
    p = fmaf(p, z, -0.00417768164f);
    p = fmaf(p, z, 0.246640727f);
    p = fmaf(p, z, 1.50140941f);
  } else {
    float z = sqrtf(w) - 3.0f;
    p = -0.000200214257f;
    p = fmaf(p, z, 0.000100950558f);
    p = fmaf(p, z, 0.00134934322f);
    p = fmaf(p, z, -0.00367342844f);
    p = fmaf(p, z, 0.00573950773f);
    p = fmaf(p, z, -0.0076224613f);
    p = fmaf(p, z, 0.00943887047f);
    p = fmaf(p, z, 1.00167406f);
    p = fmaf(p, z, 2.83297682f);
  }
  return 1.4142135623730951f * (p * u);
}

__device__ __forceinline__ unsigned short bf16r(float f) { // round-to-nearest-even
  unsigned u = __builtin_bit_cast(unsigned, f);
  return (unsigned short)((u + 0x7fffu + ((u >> 16) & 1u)) >> 16);
}
__device__ __forceinline__ float bf2f(unsigned short h) {
  return __builtin_bit_cast(float, ((unsigned)h) << 16);
}

__device__ __forceinline__ float4v mfma_bf16(short8 a, short8 b, float4v c) {
  return __builtin_amdgcn_mfma_f32_16x16x32_bf16(
      __builtin_bit_cast(bf16x8, a), __builtin_bit_cast(bf16x8, b), c, 0, 0, 0);
}

__global__ __launch_bounds__(512, 2)
void drnet_kernel(const float* __restrict__ flat_img,
                  const float* __restrict__ W_ih,
                  const float* __restrict__ W_hh,
                  const float* __restrict__ b_ih,
                  const float* __restrict__ b_hh,
                  float* __restrict__ out)
{
  __shared__ float    x_sh[ROWS * XSTR];
  __shared__ unsigned keys_sh[2 * TSTEPS];
  __shared__ short    lhi[2][ROWS * LSTR];   // latent bf16 level-0, dbuf
  __shared__ short    lmd[2][ROWS * LSTR];   // level-1
  __shared__ short    llo[2][ROWS * LSTR];   // level-2

  const int tid  = threadIdx.x;
  const int wg   = blockIdx.x;
  const int wv   = tid >> 6;
  const int lane = tid & 63;
  const int q    = lane >> 4;
  const int c    = lane & 15;

  // partitionable split: key_t = threefry((0,42), (0,t))
  if (tid < TSTEPS) {
    U2 kk = threefry(0u, 42u, 0u, (unsigned)tid);
    keys_sh[2*tid]   = kk.x;
    keys_sh[2*tid+1] = kk.y;
  }

  { // stage x: rows [wg*16, wg*16+16) of flat_img
    int i = tid * 8;
    int m = i >> 8;
    const float4v* src = (const float4v*)(flat_img + (size_t)wg * (ROWS*TSTEPS) + i);
    float4v v0 = src[0], v1 = src[1];
    float* dst = &x_sh[m * XSTR + (i & 255)];
    *(float4v*)dst       = v0;
    *((float4v*)dst + 1) = v1;
  }

  { // zero all latent level buffers
    int* p0 = (int*)&lhi[0][0];
    int* p1 = (int*)&lmd[0][0];
    int* p2 = (int*)&llo[0][0];
    for (int i = tid; i < ROWS * LSTR; i += 512) { p0[i] = 0; p1[i] = 0; p2[i] = 0; }
  }

  // persistent W_hh fragments: 3-level bf16 split, 192 VGPRs/wave.
  short8 Whi[2][8], Wmd[2][8], Wlo[2][8];
  float bias[2], wih[2];
  #pragma unroll
  for (int nt = 0; nt < 2; ++nt) {
    int g = wv*32 + nt*16 + c;
    bias[nt] = b_ih[g] + b_hh[g];
    wih[nt]  = W_ih[g];
    #pragma unroll
    for (int kk = 0; kk < 8; ++kk) {
      const float* wp = W_hh + g*HDIM + kk*32 + q*8;
      float4v w0 = *(const float4v*)wp;
      float4v w1 = *(const float4v*)(wp + 4);
      short8 h8, m8, l8;
      #pragma unroll
      for (int j2 = 0; j2 < 4; ++j2) {
        float f0 = w0[j2], f1 = w1[j2];
        unsigned short hb0 = bf16r(f0), hb1 = bf16r(f1);
        float r0 = f0 - bf2f(hb0), r1 = f1 - bf2f(hb1);
        unsigned short mb0 = bf16r(r0), mb1 = bf16r(r1);
        h8[j2] = (short)hb0; h8[j2+4] = (short)hb1;
        m8[j2] = (short)mb0; m8[j2+4] = (short)mb1;
        l8[j2]   = (short)bf16r(r0 - bf2f(mb0));
        l8[j2+4] = (short)bf16r(r1 - bf2f(mb1));
      }
      Whi[nt][kk] = h8; Wmd[nt][kk] = m8; Wlo[nt][kk] = l8;
    }
  }

  // fp32 master latent: lane owns rows q*4+r, cols wv*32+nt*16+c
  float lat[8];
  #pragma unroll
  for (int i = 0; i < 8; ++i) lat[i] = 0.0f;

  const unsigned jbase = ((unsigned)(wg*ROWS + q*4) << 8) + (unsigned)(wv*32 + c);
  const int aoff = c * LSTR + q * 8;  // A-frag: A[m=lane&15][k=quad*8+j]

  __syncthreads();

  for (int t = 0; t < TSTEPS; ++t) {
    unsigned kA = (unsigned)__builtin_amdgcn_readfirstlane((int)keys_sh[2*t]);
    unsigned kB = (unsigned)__builtin_amdgcn_readfirstlane((int)keys_sh[2*t+1]);

    const short* hb = &lhi[t & 1][0];
    const short* mb = &lmd[t & 1][0];
    const short* lb = &llo[t & 1][0];
    // SIX term products per tile (dropped: AmWl+AlWm ~2^-27, AlWl ~2^-36):
    // acc A: AhWh + AlWh + AhWl ; acc B (small terms): AmWh + AhWm + AmWm
    float4v a0a = {0,0,0,0}, a0b = {0,0,0,0};
    float4v a1a = {0,0,0,0}, a1b = {0,0,0,0};
    #pragma unroll
    for (int kk = 0; kk < 8; ++kk) {
      short8 ah = *(const short8*)(hb + aoff + kk*32);
      short8 am = *(const short8*)(mb + aoff + kk*32);
      short8 al = *(const short8*)(lb + aoff + kk*32);
      a0a = mfma_bf16(ah, Whi[0][kk], a0a);
      a0b = mfma_bf16(am, Whi[0][kk], a0b);
      a0a = mfma_bf16(al, Whi[0][kk], a0a);
      a0b = mfma_bf16(ah, Wmd[0][kk], a0b);
      a0a = mfma_bf16(ah, Wlo[0][kk], a0a);
      a0b = mfma_bf16(am, Wmd[0][kk], a0b);
      a1a = mfma_bf16(ah, Whi[1][kk], a1a);
      a1b = mfma_bf16(am, Whi[1][kk], a1b);
      a1a = mfma_bf16(al, Whi[1][kk], a1a);
      a1b = mfma_bf16(ah, Wmd[1][kk], a1b);
      a1a = mfma_bf16(ah, Wlo[1][kk], a1a);
      a1b = mfma_bf16(am, Wmd[1][kk], a1b);
    }

    // sigma_t: ts = 256-t; a=(ts+1)/257; sigma=sqrt(a(1-a)); sigma_0 == 0
    float tsf = (float)(TSTEPS - t);
    float a_t = (tsf + 1.0f) / 257.0f;
    float sig = sqrtf(a_t * (1.0f - a_t));
    float escale = 0.1f * sig;

    float xr[4];
    #pragma unroll
    for (int r = 0; r < 4; ++r) xr[r] = x_sh[(q*4 + r) * XSTR + t];

    short* nhb = &lhi[(t + 1) & 1][0];
    short* nmb = &lmd[(t + 1) & 1][0];
    short* nlb = &llo[(t + 1) & 1][0];

    #pragma unroll
    for (int nt = 0; nt < 2; ++nt) {
      #pragma unroll
      for (int r = 0; r < 4; ++r) {
        float d = nt ? (a1a[r] + a1b[r]) : (a0a[r] + a0b[r]);
        float pre = d + fmaf(xr[r], wih[nt], bias[nt]);
        // tanh with XLA clamp: |x| >= 7.90531111 -> +/-1 exactly
        float h;
        if (__builtin_fabsf(pre) >= 7.90531110763549805f) {
          h = pre > 0.0f ? 1.0f : -1.0f;
        } else {
          float e = __builtin_amdgcn_exp2f(pre * 2.8853900817779268f);
          h = fmaf(-2.0f, __builtin_amdgcn_rcpf(e + 1.0f), 1.0f);
        }
        float nl = lat[nt*4 + r] + xr[r] + h;
        if (t != 0) { // sigma_0 == 0 exactly: step-0 noise is a no-op
          unsigned j = jbase + (unsigned)(r*256 + nt*16); // = b*256 + g
          U2 rr = threefry(kA, kB, 0u, j);
          float nrm = jax_normal_from_bits(rr.x ^ rr.y);
          nl = fmaf(escale, nrm, nl);
        }
        lat[nt*4 + r] = nl;
        // 3-level bf16 store of new latent
        unsigned short hb16 = bf16r(nl);
        float r1f = nl - bf2f(hb16);
        unsigned short mb16 = bf16r(r1f);
        unsigned short lb16 = bf16r(r1f - bf2f(mb16));
        int widx = (q*4 + r) * LSTR + wv*32 + nt*16 + c;
        nhb[widx] = (short)hb16;
        nmb[widx] = (short)mb16;
        nlb[widx] = (short)lb16;
      }
    }
    __syncthreads(); // single barrier/step (reads buf t&1, writes (t+1)&1)
  }

  #pragma unroll
  for (int nt = 0; nt < 2; ++nt) {
    #pragma unroll
    for (int r = 0; r < 4; ++r)
      out[jbase + (unsigned)(r*256 + nt*16)] = lat[nt*4 + r];
  }
}

extern "C" void kernel_launch(void* const* d_in, const int* in_sizes, int n_in,
                              void* d_out, int out_size, void* d_ws, size_t ws_size,
                              hipStream_t stream) {
  // inputs: [0]=T (int, =256), [1]=flat_img (4096x256 f32), [2]=W_ih (256x1),
  // [3]=W_hh (256x256), [4]=b_ih (256), [5]=b_hh (256)
  (void)in_sizes; (void)n_in; (void)out_size; (void)d_ws; (void)ws_size;
  const float* flat_img = (const float*)d_in[1];
  const float* W_ih     = (const float*)d_in[2];
  const float* W_hh     = (const float*)d_in[3];
  const float* b_ih     = (const float*)d_in[4];
  const float* b_hh     = (const float*)d_in[5];
  drnet_kernel<<<dim3(4096 / ROWS), dim3(512), 0, stream>>>(
      flat_img, W_ih, W_hh, b_ih, b_hh, (float*)d_out);
}

// Round 6
// 1257.259 us; speedup vs baseline: 1.2099x; 1.2099x over previous
//
#include <hip/hip_runtime.h>

// DRNet scan: 256 wgs x 512 threads; each wg owns 16 batch rows, iterates all
// 256 steps locally. 6-term 3-level-bf16 MFMA split (verified: absmax 2.0).
// R6 = R5 with the LDS-zeroing OOB fixed (R5 wrote 50KB past lat6 -> stomped
// co-resident LDS, absmax 572). R5 structure kept:
//  - single MFMA chain per nt (acc 16->8 regs)
//  - merged latent LDS array (imm-offset ds ops, fewer addr regs)
//  - threefry+erfinv interleaved INTO the MFMA k-loop, noise in-place
//  - goal: live regs ~240 < 256 budget -> no scratch, MFMA||VALU overlap.

#define TSTEPS 256
#define HDIM   256
#define ROWS   16
#define LSTR   264            // shorts per tile row (pad 8)
#define TILE   (ROWS * LSTR)  // 4224 shorts = 8448 B per level
#define XSTR   260

typedef __attribute__((ext_vector_type(8))) short short8;
typedef __attribute__((ext_vector_type(4))) float float4v;
typedef __bf16 bf16x8 __attribute__((ext_vector_type(8)));

struct U2 { unsigned x, y; };

__device__ __forceinline__ void tfround(unsigned &x0, unsigned &x1, const int r) {
  x0 += x1;
  x1 = __builtin_rotateleft32(x1, r);
  x1 ^= x0;
}

// Threefry-2x32, 20 rounds (Random123 / JAX threefry2x32_p)
__device__ __forceinline__ U2 threefry(unsigned k0, unsigned k1, unsigned x0, unsigned x1) {
  unsigned k2 = k0 ^ k1 ^ 0x1BD11BDAu;
  x0 += k0; x1 += k1;
  tfround(x0,x1,13); tfround(x0,x1,15); tfround(x0,x1,26); tfround(x0,x1,6);
  x0 += k1; x1 += k2 + 1u;
  tfround(x0,x1,17); tfround(x0,x1,29); tfround(x0,x1,16); tfround(x0,x1,24);
  x0 += k2; x1 += k0 + 2u;
  tfround(x0,x1,13); tfround(x0,x1,15); tfround(x0,x1,26); tfround(x0,x1,6);
  x0 += k0; x1 += k1 + 3u;
  tfround(x0,x1,17); tfround(x0,x1,29); tfround(x0,x1,16); tfround(x0,x1,24);
  x0 += k1; x1 += k2 + 4u;
  tfround(x0,x1,13); tfround(x0,x1,15); tfround(x0,x1,26); tfround(x0,x1,6);
  x0 += k2; x1 += k0 + 5u;
  return {x0, x1};
}

// JAX uniform(lo=nextafter(-1,0), 1) -> sqrt(2)*erf_inv(u), XLA ErfInv32.
__device__ __forceinline__ float jax_normal_from_bits(unsigned bits) {
#pragma clang fp contract(off)
  const float LO = __builtin_bit_cast(float, 0xBF7FFFFFu); // nextafter(-1,0)
  float f = __builtin_bit_cast(float, (bits >> 9) | 0x3f800000u) - 1.0f;
  float u = fmaf(f, 2.0f, LO);
  u = fmaxf(u, LO);
  float t1 = u * u;             // rounded u^2 (as XLA's x*x)
  float s  = 1.0f - t1;         // Sterbenz-exact in the tail; unfused
  float w  = -0.6931471805599453f * __builtin_amdgcn_logf(s);
  float p;
  if (w < 5.0f) {
    float z = w - 2.5f;
    p = 2.81022636e-08f;
    p = fmaf(p, z, 3.43273939e-07f);
    p = fmaf(p, z, -3.5233877e-06f);
    p = fmaf(p, z, -4.39150654e-06f);
    p = fmaf(p, z, 0.00021858087f);
    p = fmaf(p, z, -0.00125372503f);
    p = fmaf(p, z, -0.00417768164f);
    p = fmaf(p, z, 0.246640727f);
    p = fmaf(p, z, 1.50140941f);
  } else {
    float z = sqrtf(w) - 3.0f;
    p = -0.000200214257f;
    p = fmaf(p, z, 0.000100950558f);
    p = fmaf(p, z, 0.00134934322f);
    p = fmaf(p, z, -0.00367342844f);
    p = fmaf(p, z, 0.00573950773f);
    p = fmaf(p, z, -0.0076224613f);
    p = fmaf(p, z, 0.00943887047f);
    p = fmaf(p, z, 1.00167406f);
    p = fmaf(p, z, 2.83297682f);
  }
  return 1.4142135623730951f * (p * u);
}

__device__ __forceinline__ unsigned short bf16r(float f) { // round-to-nearest-even
  unsigned u = __builtin_bit_cast(unsigned, f);
  return (unsigned short)((u + 0x7fffu + ((u >> 16) & 1u)) >> 16);
}
__device__ __forceinline__ float bf2f(unsigned short h) {
  return __builtin_bit_cast(float, ((unsigned)h) << 16);
}

__device__ __forceinline__ float4v mfma_bf16(short8 a, short8 b, float4v c) {
  return __builtin_amdgcn_mfma_f32_16x16x32_bf16(
      __builtin_bit_cast(bf16x8, a), __builtin_bit_cast(bf16x8, b), c, 0, 0, 0);
}

__global__ __launch_bounds__(512, 2)
void drnet_kernel(const float* __restrict__ flat_img,
                  const float* __restrict__ W_ih,
                  const float* __restrict__ W_hh,
                  const float* __restrict__ b_ih,
                  const float* __restrict__ b_hh,
                  float* __restrict__ out)
{
  __shared__ float    x_sh[ROWS * XSTR];
  __shared__ unsigned keys_sh[2 * TSTEPS];
  // merged latent store: [buf][level][tile] -> single base + imm offsets
  __shared__ short    lat6[2][3][TILE];

  const int tid  = threadIdx.x;
  const int wg   = blockIdx.x;
  const int wv   = tid >> 6;
  const int lane = tid & 63;
  const int q    = lane >> 4;
  const int c    = lane & 15;

  // partitionable split: key_t = threefry((0,42), (0,t))
  if (tid < TSTEPS) {
    U2 kk = threefry(0u, 42u, 0u, (unsigned)tid);
    keys_sh[2*tid]   = kk.x;
    keys_sh[2*tid+1] = kk.y;
  }

  { // stage x: rows [wg*16, wg*16+16) of flat_img
    int i = tid * 8;
    int m = i >> 8;
    const float4v* src = (const float4v*)(flat_img + (size_t)wg * (ROWS*TSTEPS) + i);
    float4v v0 = src[0], v1 = src[1];
    float* dst = &x_sh[m * XSTR + (i & 255)];
    *(float4v*)dst       = v0;
    *((float4v*)dst + 1) = v1;
  }

  { // zero ALL of lat6: 2*3*TILE shorts == 3*TILE ints. (R5 bug: a second
    // store at p0[i+3*TILE] ran 50KB past the array -> LDS corruption.)
    int* p0 = (int*)&lat6[0][0][0];
    for (int i = tid; i < 3 * TILE; i += 512) p0[i] = 0;
  }

  // persistent W_hh fragments: 3-level bf16 split, 192 regs/lane.
  short8 Whi[2][8], Wmd[2][8], Wlo[2][8];
  float bias[2], wih[2];
  #pragma unroll
  for (int nt = 0; nt < 2; ++nt) {
    int g = wv*32 + nt*16 + c;
    bias[nt] = b_ih[g] + b_hh[g];
    wih[nt]  = W_ih[g];
    #pragma unroll
    for (int kk = 0; kk < 8; ++kk) {
      const float* wp = W_hh + g*HDIM + kk*32 + q*8;
      float4v w0 = *(const float4v*)wp;
      float4v w1 = *(const float4v*)(wp + 4);
      short8 h8, m8, l8;
      #pragma unroll
      for (int j2 = 0; j2 < 4; ++j2) {
        float f0 = w0[j2], f1 = w1[j2];
        unsigned short hb0 = bf16r(f0), hb1 = bf16r(f1);
        float r0 = f0 - bf2f(hb0), r1 = f1 - bf2f(hb1);
        unsigned short mb0 = bf16r(r0), mb1 = bf16r(r1);
        h8[j2] = (short)hb0; h8[j2+4] = (short)hb1;
        m8[j2] = (short)mb0; m8[j2+4] = (short)mb1;
        l8[j2]   = (short)bf16r(r0 - bf2f(mb0));
        l8[j2+4] = (short)bf16r(r1 - bf2f(mb1));
      }
      Whi[nt][kk] = h8; Wmd[nt][kk] = m8; Wlo[nt][kk] = l8;
    }
  }

  // fp32 master latent: lane owns rows q*4+r, cols wv*32+nt*16+c; idx = nt*4+r
  float lat[8];
  #pragma unroll
  for (int i = 0; i < 8; ++i) lat[i] = 0.0f;

  const unsigned jbase = ((unsigned)(wg*ROWS + q*4) << 8) + (unsigned)(wv*32 + c);
  const int aoff = c * LSTR + q * 8;              // A-frag read offset (shorts)
  const int woff = (q*4) * LSTR + wv*32 + c;      // write offset base (shorts)

  __syncthreads();

  for (int t = 0; t < TSTEPS; ++t) {
    unsigned kA = (unsigned)__builtin_amdgcn_readfirstlane((int)keys_sh[2*t]);
    unsigned kB = (unsigned)__builtin_amdgcn_readfirstlane((int)keys_sh[2*t+1]);

    // sigma_t: ts=256-t; a=(ts+1)/257; sigma=sqrt(a(1-a)); exactly 0 at t=0
    float tsf = (float)(TSTEPS - t);
    float a_t = (tsf + 1.0f) / 257.0f;
    float escale = 0.1f * sqrtf(a_t * (1.0f - a_t));

    const short* rb = &lat6[t & 1][0][aoff];        // + lv*TILE + kk*32 (imm)
    short*       wb = &lat6[(t + 1) & 1][0][woff];  // + lv*TILE + r*LSTR + nt*16

    float4v a0 = {0.f, 0.f, 0.f, 0.f};
    float4v a1 = {0.f, 0.f, 0.f, 0.f};
    // k-loop with interleaved RNG: 12 MFMAs + 1 cipher+erfinv per iteration,
    // so the matrix pipe and VALU run concurrently within each wave.
    #pragma unroll
    for (int kk = 0; kk < 8; ++kk) {
      short8 ah = *(const short8*)(rb + 0*TILE + kk*32);
      short8 am = *(const short8*)(rb + 1*TILE + kk*32);
      short8 al = *(const short8*)(rb + 2*TILE + kk*32);
      a0 = mfma_bf16(ah, Whi[0][kk], a0);
      a1 = mfma_bf16(ah, Whi[1][kk], a1);
      a0 = mfma_bf16(am, Whi[0][kk], a0);
      a1 = mfma_bf16(am, Whi[1][kk], a1);
      a0 = mfma_bf16(al, Whi[0][kk], a0);
      a1 = mfma_bf16(al, Whi[1][kk], a1);
      a0 = mfma_bf16(ah, Wmd[0][kk], a0);
      a1 = mfma_bf16(ah, Wmd[1][kk], a1);
      a0 = mfma_bf16(am, Wmd[0][kk], a0);
      a1 = mfma_bf16(am, Wmd[1][kk], a1);
      a0 = mfma_bf16(ah, Wlo[0][kk], a0);
      a1 = mfma_bf16(ah, Wlo[1][kk], a1);
      // noise for element idx=kk (nt=kk>>2, r=kk&3): j = b*256 + g
      {
        unsigned j = jbase + (unsigned)((kk & 3)*256 + (kk >> 2)*16);
        U2 rr = threefry(kA, kB, 0u, j);
        float nrm = jax_normal_from_bits(rr.x ^ rr.y);
        lat[kk] = fmaf(escale, nrm, lat[kk]);  // in-place; escale=0 at t=0
      }
    }

    float xr[4];
    #pragma unroll
    for (int r = 0; r < 4; ++r) xr[r] = x_sh[(q*4 + r) * XSTR + t];

    #pragma unroll
    for (int nt = 0; nt < 2; ++nt) {
      #pragma unroll
      for (int r = 0; r < 4; ++r) {
        float d = nt ? a1[r] : a0[r];
        float pre = d + fmaf(xr[r], wih[nt], bias[nt]);
        // tanh with XLA clamp: |x| >= 7.90531111 -> +/-1 exactly
        float h;
        if (__builtin_fabsf(pre) >= 7.90531110763549805f) {
          h = pre > 0.0f ? 1.0f : -1.0f;
        } else {
          float e = __builtin_amdgcn_exp2f(pre * 2.8853900817779268f);
          h = fmaf(-2.0f, __builtin_amdgcn_rcpf(e + 1.0f), 1.0f);
        }
        float nl = lat[nt*4 + r] + xr[r] + h;   // noise already folded in
        lat[nt*4 + r] = nl;
        // 3-level bf16 store of new latent (imm-offset writes)
        unsigned short hb16 = bf16r(nl);
        float r1f = nl - bf2f(hb16);
        unsigned short mb16 = bf16r(r1f);
        unsigned short lb16 = bf16r(r1f - bf2f(mb16));
        short* wp = wb + r*LSTR + nt*16;
        wp[0*TILE] = (short)hb16;
        wp[1*TILE] = (short)mb16;
        wp[2*TILE] = (short)lb16;
      }
    }
    __syncthreads(); // single barrier/step (reads buf t&1, writes (t+1)&1)
  }

  #pragma unroll
  for (int nt = 0; nt < 2; ++nt) {
    #pragma unroll
    for (int r = 0; r < 4; ++r)
      out[jbase + (unsigned)(r*256 + nt*16)] = lat[nt*4 + r];
  }
}

extern "C" void kernel_launch(void* const* d_in, const int* in_sizes, int n_in,
                              void* d_out, int out_size, void* d_ws, size_t ws_size,
                              hipStream_t stream) {
  // inputs: [0]=T (int, =256), [1]=flat_img (4096x256 f32), [2]=W_ih (256x1),
  // [3]=W_hh (256x256), [4]=b_ih (256), [5]=b_hh (256)
  (void)in_sizes; (void)n_in; (void)out_size; (void)d_ws; (void)ws_size;
  const float* flat_img = (const float*)d_in[1];
  const float* W_ih     = (const float*)d_in[2];
  const float* W_hh     = (const float*)d_in[3];
  const float* b_ih     = (const float*)d_in[4];
  const float* b_hh     = (const float*)d_in[5];
  drnet_kernel<<<dim3(4096 / ROWS), dim3(512), 0, stream>>>(
      flat_img, W_ih, W_hh, b_ih, b_hh, (float*)d_out);
}